// Round 16
// baseline (388.664 us; speedup 1.0000x reference)
//
#include <hip/hip_runtime.h>

#define BN 4
#define CH 64          // CIN*UM = COUT*UM
#define HH 128
#define WW 128
#define PIX (HH*WW)

// workspace layout (float offsets)
#define OFF_WL  0                    // packed [4 ocg][64 c][9 tap][16 oc] = 36864
#define OFF_S   36864                // [2][64]      = 128
#define OFF_CS  36992                // [4][2][128][128] = 131072

__device__ __forceinline__ int iclamp(int v, int lo, int hi) {
    return v < lo ? lo : (v > hi ? hi : v);
}

// ---- single prep kernel, 3 roles by block range:
//  [0,144)    : Wl packed [ocg][c][tap][16] ; ker[oc, c, p, q], tap = q*3+p
//  144        : S[u][oc] via factorized sum (== sum of ker over i,taps)
//  [145, 273) : cs[b][u][pix] = sum_i x[b][2i+u][pix]   (float4, coalesced)
__global__ __launch_bounds__(256) void k_prep(const float* __restrict__ params,
                                              const float* __restrict__ basis,
                                              const float* __restrict__ x,
                                              float* __restrict__ Wl,
                                              float* __restrict__ S,
                                              float* __restrict__ cs) {
    int bx = blockIdx.x;
    if (bx < 144) {
        int idx = bx * 256 + threadIdx.x;      // < 36864
        int oc  = idx & 63;
        int tap = (idx >> 6) % 9;
        int c   = idx / 576;
        int q = tap / 3, p = tap % 3;
        int o = oc >> 1, g = oc & 1;
        int i = c >> 1, u = c & 1;
        float s = 0.f;
        #pragma unroll
        for (int n = 0; n < 4; ++n)
            #pragma unroll
            for (int d = 0; d < 4; ++d)
                s = fmaf(params[((o * 32 + i) * 4 + n) * 4 + d],
                         basis[((((n * 4 + d) * 3 + p) * 3 + q) * 2 + g) * 2 + u], s);
        // packed: [ocg][c][tap][oc&15]
        Wl[(((oc >> 4) * 64 + c) * 9 + tap) * 16 + (oc & 15)] = s;
    } else if (bx == 144) {
        int t = threadIdx.x;
        if (t < 128) {
            int u = t >> 6, oc = t & 63;
            int o = oc >> 1, g = oc & 1;
            float s = 0.f;
            #pragma unroll
            for (int nd = 0; nd < 16; ++nd) {
                int n = nd >> 2, d = nd & 3;
                float pa = 0.f;
                for (int i = 0; i < 32; ++i)
                    pa += params[((o * 32 + i) * 4 + n) * 4 + d];
                float sb = 0.f;
                #pragma unroll
                for (int e = 0; e < 3; ++e)
                    #pragma unroll
                    for (int f = 0; f < 3; ++f)
                        sb += basis[((((n * 4 + d) * 3 + e) * 3 + f) * 2 + g) * 2 + u];
                s = fmaf(pa, sb, s);
            }
            S[t] = s;
        }
    } else {
        int idx = (bx - 145) * 256 + threadIdx.x;   // < 32768
        int pq  = idx & (PIX / 4 - 1);
        int u   = (idx >> 12) & 1;
        int b   = idx >> 13;
        const float4* xb = (const float4*)x;
        float4 s = make_float4(0.f, 0.f, 0.f, 0.f);
        #pragma unroll
        for (int i = 0; i < 32; ++i) {
            float4 v = xb[(size_t)(b * CH + 2 * i + u) * (PIX / 4) + pq];
            s.x += v.x; s.y += v.y; s.z += v.z; s.w += v.w;
        }
        ((float4*)cs)[(b * 2 + u) * (PIX / 4) + pq] = s;
    }
}

// ---- main: split-K across wave-halves. 16x8 px tile, 16 oc/thread,
//      waves 0-1 compute ch 0-31, waves 2-3 compute ch 32-63 (disjoint
//      traffic -> 2x TLP at zero extra L1/K$ cost), LDS combine once.
__global__ __launch_bounds__(256, 8) void k_main(
    const float* __restrict__ x,     // [4][64][128][128]
    const float* __restrict__ Wl,    // packed [4][64][9][16]
    const float* __restrict__ S,     // [2][64]
    const float* __restrict__ bias,  // [64]
    const float* __restrict__ cs,    // [4][2][128][128]
    const float* __restrict__ bptr,  // scalar b
    float* __restrict__ out)         // [4][64][128][128]
{
    __shared__ float red[16 * 128];   // 8 KB, coalesced combine buffer

    int tile = blockIdx.x;            // 128 tiles: 8 wide x 16 tall, 16x8 px
    int ocg  = blockIdx.y;            // 4 groups of 16 oc
    int b    = blockIdx.z;
    int t    = threadIdx.x;
    int px   = t & 127;
    int half = t >> 7;                // wave-uniform: waves 0-1 -> 0, 2-3 -> 1
    int ty = px >> 4, tx = px & 15;
    int h = (tile >> 3) * 8 + ty;
    int w = (tile & 7) * 16 + tx;

    int hm = h > 0 ? h - 1 : 0, hp = h < HH - 1 ? h + 1 : HH - 1;
    int wm = w > 0 ? w - 1 : 0, wp = w < WW - 1 ? w + 1 : WW - 1;
    int rowoff[3] = { hm * WW, h * WW, hp * WW };
    int coloff[3] = { wm, w, wp };
    int off[9];
    #pragma unroll
    for (int r = 0; r < 3; ++r)
        #pragma unroll
        for (int p = 0; p < 3; ++p)
            off[r * 3 + p] = rowoff[r] + coloff[p];

    float acc[16];
    #pragma unroll
    for (int j = 0; j < 16; ++j) acc[j] = 0.f;

    const float* xb = x + (size_t)b * CH * PIX + (size_t)(half * 32) * PIX;
    const float* wc = Wl + (size_t)ocg * 64 * 144 + (size_t)(half * 32) * 144;

    // prologue: window for first channel of this half
    float xA[9];
    #pragma unroll
    for (int k = 0; k < 9; ++k) xA[k] = xb[off[k]];

    for (int c = 0; c < 32; ++c) {
        // depth-1 prefetch of next channel (hidden under FMAs + TLP)
        const float* xn = xb + (size_t)(c + 1 < 32 ? c + 1 : c) * PIX;
        float xN[9];
        #pragma unroll
        for (int k = 0; k < 9; ++k) xN[k] = xn[off[k]];

        const float* wt = wc + c * 144;
        #pragma unroll
        for (int tap = 0; tap < 9; ++tap) {
            float xt = xA[tap];
            #pragma unroll
            for (int j = 0; j < 16; ++j)
                acc[j] = fmaf(xt, wt[tap * 16 + j], acc[j]);   // wave-uniform -> s_load
        }
        #pragma unroll
        for (int k = 0; k < 9; ++k) xA[k] = xN[k];
    }

    // combine halves: half1 writes coalesced, half0 adds
    if (half) {
        #pragma unroll
        for (int j = 0; j < 16; ++j) red[j * 128 + px] = acc[j];
    }
    __syncthreads();
    if (!half) {
        #pragma unroll
        for (int j = 0; j < 16; ++j) acc[j] += red[j * 128 + px];

        // epilogue: avg = box3x3_edge(cs)/288 (cs is L2-hot)
        int pix = h * WW + w;
        const float* c0p = cs + (size_t)(b * 2 + 0) * PIX;
        const float* c1p = cs + (size_t)(b * 2 + 1) * PIX;
        int r0 = rowoff[0], r1 = rowoff[1], r2 = rowoff[2];
        float a0 = (c0p[r0 + wm] + c0p[r0 + w] + c0p[r0 + wp]
                  + c0p[r1 + wm] + c0p[r1 + w] + c0p[r1 + wp]
                  + c0p[r2 + wm] + c0p[r2 + w] + c0p[r2 + wp]) * (1.0f / 288.0f);
        float a1 = (c1p[r0 + wm] + c1p[r0 + w] + c1p[r0 + wp]
                  + c1p[r1 + wm] + c1p[r1 + w] + c1p[r1 + wp]
                  + c1p[r2 + wm] + c1p[r2 + w] + c1p[r2 + wp]) * (1.0f / 288.0f);
        float bthr = bptr[0];

        float* ob = out + (size_t)b * CH * PIX + pix;
        #pragma unroll
        for (int j = 0; j < 16; j += 2) {
            int oc = ocg * 16 + j;
            float t0 = acc[j]     - a0 * S[oc]     - a1 * S[64 + oc]     + bias[oc];
            float t1 = acc[j + 1] - a0 * S[oc + 1] - a1 * S[64 + oc + 1] + bias[oc + 1];
            float n = sqrtf(t0 * t0 + t1 * t1);
            float r0v, r1v;
            if (n - bthr <= 0.f) { r0v = 0.f; r1v = 0.f; }
            else { r0v = t0 / n; r1v = t1 / n; }
            ob[(size_t)oc * PIX]       = r0v + a0;
            ob[(size_t)(oc + 1) * PIX] = r1v + a1;
        }
    }
}

extern "C" void kernel_launch(void* const* d_in, const int* in_sizes, int n_in,
                              void* d_out, int out_size, void* d_ws, size_t ws_size,
                              hipStream_t stream) {
    const float* xx     = (const float*)d_in[0];
    const float* params = (const float*)d_in[1];
    const float* basis  = (const float*)d_in[2];
    const float* bias   = (const float*)d_in[3];
    const float* bptr   = (const float*)d_in[4];
    float* out = (float*)d_out;
    float* ws  = (float*)d_ws;

    float* Wl  = ws + OFF_WL;
    float* S   = ws + OFF_S;
    float* cs  = ws + OFF_CS;

    k_prep<<<273, 256, 0, stream>>>(params, basis, xx, Wl, S, cs);

    dim3 grid(128, 4, BN);
    k_main<<<grid, 256, 0, stream>>>(xx, Wl, S, bias, cs, bptr, out);
}

// Round 17
// 140.527 us; speedup vs baseline: 2.7658x; 2.7658x over previous
//
#include <hip/hip_runtime.h>

#define BN 4
#define CH 64          // CIN*UM = COUT*UM
#define HH 128
#define WW 128
#define PIX (HH*WW)

// workspace layout (float offsets)
#define OFF_WL  0                    // packed [4 ocg][64 c][9 tap][16 oc] = 36864
#define OFF_S   36864                // [2][64]      = 128
#define OFF_CS  36992                // [4][2][128][128] = 131072

__device__ __forceinline__ int iclamp(int v, int lo, int hi) {
    return v < lo ? lo : (v > hi ? hi : v);
}

// ---- single prep kernel, 3 roles by block range:
//  [0,144)    : Wl packed [ocg][c][tap][16] ; ker[oc, c, p, q], tap = q*3+p
//  144        : S[u][oc] via factorized sum (== sum of ker over i,taps)
//  [145, 273) : cs[b][u][pix] = sum_i x[b][2i+u][pix]   (float4, coalesced)
__global__ __launch_bounds__(256) void k_prep(const float* __restrict__ params,
                                              const float* __restrict__ basis,
                                              const float* __restrict__ x,
                                              float* __restrict__ Wl,
                                              float* __restrict__ S,
                                              float* __restrict__ cs) {
    int bx = blockIdx.x;
    if (bx < 144) {
        int idx = bx * 256 + threadIdx.x;      // < 36864
        int oc  = idx & 63;
        int tap = (idx >> 6) % 9;
        int c   = idx / 576;
        int q = tap / 3, p = tap % 3;
        int o = oc >> 1, g = oc & 1;
        int i = c >> 1, u = c & 1;
        float s = 0.f;
        #pragma unroll
        for (int n = 0; n < 4; ++n)
            #pragma unroll
            for (int d = 0; d < 4; ++d)
                s = fmaf(params[((o * 32 + i) * 4 + n) * 4 + d],
                         basis[((((n * 4 + d) * 3 + p) * 3 + q) * 2 + g) * 2 + u], s);
        // packed: [ocg][c][tap][oc&15]
        Wl[(((oc >> 4) * 64 + c) * 9 + tap) * 16 + (oc & 15)] = s;
    } else if (bx == 144) {
        int t = threadIdx.x;
        if (t < 128) {
            int u = t >> 6, oc = t & 63;
            int o = oc >> 1, g = oc & 1;
            float s = 0.f;
            #pragma unroll
            for (int nd = 0; nd < 16; ++nd) {
                int n = nd >> 2, d = nd & 3;
                float pa = 0.f;
                for (int i = 0; i < 32; ++i)
                    pa += params[((o * 32 + i) * 4 + n) * 4 + d];
                float sb = 0.f;
                #pragma unroll
                for (int e = 0; e < 3; ++e)
                    #pragma unroll
                    for (int f = 0; f < 3; ++f)
                        sb += basis[((((n * 4 + d) * 3 + e) * 3 + f) * 2 + g) * 2 + u];
                s = fmaf(pa, sb, s);
            }
            S[t] = s;
        }
    } else {
        int idx = (bx - 145) * 256 + threadIdx.x;   // < 32768
        int pq  = idx & (PIX / 4 - 1);
        int u   = (idx >> 12) & 1;
        int b   = idx >> 13;
        const float4* xb = (const float4*)x;
        float4 s = make_float4(0.f, 0.f, 0.f, 0.f);
        #pragma unroll
        for (int i = 0; i < 32; ++i) {
            float4 v = xb[(size_t)(b * CH + 2 * i + u) * (PIX / 4) + pq];
            s.x += v.x; s.y += v.y; s.z += v.z; s.w += v.w;
        }
        ((float4*)cs)[(b * 2 + u) * (PIX / 4) + pq] = s;
    }
}

// ---- main: NO LDS. 16 oc/thread, 1 px/thread, 16x16 tiles.
//      Per-wave channel ROTATION desynchronizes the 4 waves of a block so
//      one wave's load/stall phase overlaps the others' FMA phase.
__global__ __launch_bounds__(256, 4) void k_main(
    const float* __restrict__ x,     // [4][64][128][128]
    const float* __restrict__ Wl,    // packed [4][64][9][16]
    const float* __restrict__ S,     // [2][64]
    const float* __restrict__ bias,  // [64]
    const float* __restrict__ cs,    // [4][2][128][128]
    const float* __restrict__ bptr,  // scalar b
    float* __restrict__ out)         // [4][64][128][128]
{
    int tile = blockIdx.x;            // 8x8 tiles of 16x16
    int ocg  = blockIdx.y;            // 4 groups of 16 oc
    int b    = blockIdx.z;
    int ty = threadIdx.x >> 4, tx = threadIdx.x & 15;
    int h = (tile >> 3) * 16 + ty;
    int w = (tile & 7) * 16 + tx;

    // wave-uniform channel rotation, forced into an SGPR so weight reads
    // remain s_load
    int crot = __builtin_amdgcn_readfirstlane((threadIdx.x >> 6) << 4);

    int hm = h > 0 ? h - 1 : 0, hp = h < HH - 1 ? h + 1 : HH - 1;
    int wm = w > 0 ? w - 1 : 0, wp = w < WW - 1 ? w + 1 : WW - 1;
    int rowoff[3] = { hm * WW, h * WW, hp * WW };
    int coloff[3] = { wm, w, wp };
    int off[9];
    #pragma unroll
    for (int r = 0; r < 3; ++r)
        #pragma unroll
        for (int p = 0; p < 3; ++p)
            off[r * 3 + p] = rowoff[r] + coloff[p];

    float acc[16];
    #pragma unroll
    for (int j = 0; j < 16; ++j) acc[j] = 0.f;

    const float* xb = x + (size_t)b * CH * PIX;
    const float* wb = Wl + (size_t)ocg * 64 * 144;   // [c][tap][16]

    #pragma unroll 4
    for (int ci = 0; ci < CH; ++ci) {
        int c = (ci + crot) & 63;                    // SALU
        const float* xc = xb + (size_t)c * PIX;
        const float* wc = wb + (size_t)c * 144;
        float xv[9];
        #pragma unroll
        for (int k = 0; k < 9; ++k) xv[k] = xc[off[k]];
        #pragma unroll
        for (int tap = 0; tap < 9; ++tap) {
            float xt = xv[tap];
            #pragma unroll
            for (int j = 0; j < 16; ++j)
                acc[j] = fmaf(xt, wc[tap * 16 + j], acc[j]);   // s_load weights
        }
    }

    // epilogue: avg = box3x3_edge(cs)/288 (cs is L2-hot)
    int pix = h * WW + w;
    const float* c0p = cs + (size_t)(b * 2 + 0) * PIX;
    const float* c1p = cs + (size_t)(b * 2 + 1) * PIX;
    int r0 = rowoff[0], r1 = rowoff[1], r2 = rowoff[2];
    float a0 = (c0p[r0 + wm] + c0p[r0 + w] + c0p[r0 + wp]
              + c0p[r1 + wm] + c0p[r1 + w] + c0p[r1 + wp]
              + c0p[r2 + wm] + c0p[r2 + w] + c0p[r2 + wp]) * (1.0f / 288.0f);
    float a1 = (c1p[r0 + wm] + c1p[r0 + w] + c1p[r0 + wp]
              + c1p[r1 + wm] + c1p[r1 + w] + c1p[r1 + wp]
              + c1p[r2 + wm] + c1p[r2 + w] + c1p[r2 + wp]) * (1.0f / 288.0f);
    float bthr = bptr[0];

    float* ob = out + (size_t)b * CH * PIX + pix;
    #pragma unroll
    for (int j = 0; j < 16; j += 2) {
        int oc = ocg * 16 + j;
        float t0 = acc[j]     - a0 * S[oc]     - a1 * S[64 + oc]     + bias[oc];
        float t1 = acc[j + 1] - a0 * S[oc + 1] - a1 * S[64 + oc + 1] + bias[oc + 1];
        float n = sqrtf(t0 * t0 + t1 * t1);
        float r0v, r1v;
        if (n - bthr <= 0.f) { r0v = 0.f; r1v = 0.f; }
        else { r0v = t0 / n; r1v = t1 / n; }
        ob[(size_t)oc * PIX]       = r0v + a0;
        ob[(size_t)(oc + 1) * PIX] = r1v + a1;
    }
}

extern "C" void kernel_launch(void* const* d_in, const int* in_sizes, int n_in,
                              void* d_out, int out_size, void* d_ws, size_t ws_size,
                              hipStream_t stream) {
    const float* xx     = (const float*)d_in[0];
    const float* params = (const float*)d_in[1];
    const float* basis  = (const float*)d_in[2];
    const float* bias   = (const float*)d_in[3];
    const float* bptr   = (const float*)d_in[4];
    float* out = (float*)d_out;
    float* ws  = (float*)d_ws;

    float* Wl  = ws + OFF_WL;
    float* S   = ws + OFF_S;
    float* cs  = ws + OFF_CS;

    k_prep<<<273, 256, 0, stream>>>(params, basis, xx, Wl, S, cs);

    dim3 grid(64, 4, BN);
    k_main<<<grid, 256, 0, stream>>>(xx, Wl, S, bias, cs, bptr, out);
}